// Round 4
// baseline (219.057 us; speedup 1.0000x reference)
//
#include <hip/hip_runtime.h>
#include <hip/hip_bf16.h>

typedef __attribute__((ext_vector_type(8))) short short8_t;
typedef __attribute__((ext_vector_type(4))) float f32x4_t;

#define NOUT 8192
#define NIN 32768
#define MTOT 262144.0f   // B * NOUT
#define ST_STRIPES 64

#define MF(a,b,c) __builtin_amdgcn_mfma_f32_16x16x32_bf16((a),(b),(c),0,0,0)

static __device__ __forceinline__ float bf2f(ushort u) {
    union { float f; unsigned int i; } x; x.i = ((unsigned int)u) << 16; return x.f;
}
static __device__ __forceinline__ ushort f2bfx(float f) {
    union { __hip_bfloat16 h; ushort u; } v;
    v.h = __float2bfloat16(f);   // hw v_cvt RNE on gfx950
    return v.u;
}

// BN1+ReLU on 8 packed bf16 with per-lane register coefficients (8-ch group)
static __device__ __forceinline__ int4 bn8(int4 v, const float* a8, const float* c8) {
    ushort* pv = (ushort*)&v;
    #pragma unroll
    for (int e = 0; e < 8; ++e)
        pv[e] = f2bfx(fmaxf(a8[e] * bf2f(pv[e]) + c8[e], 0.f));
    return v;
}

// ---- x [32][32][32768] f32  ->  xt [32768][1024] bf16 (row = b*32+i) ----
__global__ __launch_bounds__(256) void transpose_x_kernel(
    const float* __restrict__ x, ushort* __restrict__ xt)
{
    __shared__ ushort T[64][66];
    const int tid = threadIdx.x;
    const int n0 = blockIdx.x * 64, c0 = blockIdx.y * 64;
    const int lane64 = tid & 63, rb = (tid >> 6) * 16;
    #pragma unroll
    for (int r = 0; r < 16; ++r) {
        int c_l = rb + r;
        T[c_l][lane64] = f2bfx(x[(size_t)(c0 + c_l) * NIN + n0 + lane64]);
    }
    __syncthreads();
    #pragma unroll
    for (int r = 0; r < 16; ++r) {
        int n_l = rb + r;
        xt[(size_t)(n0 + n_l) * 1024 + c0 + lane64] = T[lane64][n_l];
    }
}

// ---- weight prep (+ zero the stats stripes) ----
__global__ __launch_bounds__(256) void prep_w_kernel(
    const float* __restrict__ W1, const float* __restrict__ W2,
    const float* __restrict__ We,
    ushort* __restrict__ w1p, ushort* __restrict__ w2p, ushort* __restrict__ wep,
    float* __restrict__ stz)
{
    int t = blockIdx.x * 256 + threadIdx.x;
    const int N1 = 9 * 64 * 32, N2 = 9 * 64 * 64, N3 = 64 * 32;
    if (t < 3 * ST_STRIPES * 128) stz[t] = 0.f;
    if (t < N1) {
        int k = t >> 11, rem = t & 2047, o = rem >> 5, i = rem & 31;
        w1p[t] = f2bfx(W1[o * 288 + i * 9 + k]);
    } else if (t < N1 + N2) {
        int t2 = t - N1;
        int k = t2 >> 12, rem = t2 & 4095, o = rem >> 6, ci = rem & 63;
        w2p[t2] = f2bfx(W2[o * 576 + ci * 9 + k]);
    } else if (t < N1 + N2 + N3) {
        int t3 = t - N1 - N2;
        wep[t3] = f2bfx(We[t3]);
    }
}

// ---- conv1: wave-private pipeline. 4 waves/block, each owns one n (32 b x 64 o, K=288) ----
__global__ __launch_bounds__(256) void conv1_kernel(
    const ushort* __restrict__ xt, const int* __restrict__ idx1,
    const ushort* __restrict__ w1p, ushort* __restrict__ out1,
    float* __restrict__ st)
{
    __shared__ __align__(16) ushort As[4 * 2 * 32 * 40];   // per-wave double-buffered A
    __shared__ float Ls[128];
    const int tid = threadIdx.x;
    const int lane = tid & 63, wv = tid >> 6;
    const int n = __builtin_amdgcn_readfirstlane(blockIdx.x * 4 + wv);
    const int bb = lane >> 1, hf = lane & 1;
    const int fr = (lane & 15) * 40, fc = (lane >> 4) * 8;
    ushort* Ab0 = As + wv * (2 * 32 * 40);
    ushort* Ab1 = Ab0 + 32 * 40;
    const int* idxn = idx1 + n * 9;
    const ushort* wbase = w1p + (lane & 15) * 32 + fc;

    if (tid < 128) Ls[tid] = 0.f;
    __syncthreads();

    f32x4_t acc[2][4];
    #pragma unroll
    for (int m = 0; m < 2; ++m)
        #pragma unroll
        for (int nt = 0; nt < 4; ++nt) acc[m][nt] = (f32x4_t){0.f, 0.f, 0.f, 0.f};

    int4 A0[2], A1[2];

#define C1_LOAD(K, A) { \
    const ushort* rp = xt + (size_t)idxn[K] * 1024 + bb * 32 + hf * 16; \
    A[0] = *(const int4*)rp; A[1] = *(const int4*)(rp + 8); }

#define C1_BODY(K, A, ab) { \
    const ushort* wp = wbase + (K) * 2048; \
    short8_t b0 = *(const short8_t*)(wp); \
    short8_t b1 = *(const short8_t*)(wp + 512); \
    short8_t b2 = *(const short8_t*)(wp + 1024); \
    short8_t b3 = *(const short8_t*)(wp + 1536); \
    ushort* wr = (ab) + bb * 40 + hf * 16; \
    *(int4*)wr = A[0]; *(int4*)(wr + 8) = A[1]; \
    asm volatile("" ::: "memory"); \
    short8_t af0 = *(const short8_t*)((ab) + fr + fc); \
    short8_t af1 = *(const short8_t*)((ab) + fr + 640 + fc); \
    asm volatile("" ::: "memory"); \
    acc[0][0] = MF(af0, b0, acc[0][0]); acc[1][0] = MF(af1, b0, acc[1][0]); \
    acc[0][1] = MF(af0, b1, acc[0][1]); acc[1][1] = MF(af1, b1, acc[1][1]); \
    acc[0][2] = MF(af0, b2, acc[0][2]); acc[1][2] = MF(af1, b2, acc[1][2]); \
    acc[0][3] = MF(af0, b3, acc[0][3]); acc[1][3] = MF(af1, b3, acc[1][3]); }

    C1_LOAD(0, A0);
    for (int t = 0; t < 4; ++t) {
        C1_LOAD(2 * t + 1, A1);
        C1_BODY(2 * t, A0, Ab0);
        C1_LOAD(2 * t + 2, A0);
        C1_BODY(2 * t + 1, A1, Ab1);
    }
    C1_BODY(8, A0, Ab0);
#undef C1_LOAD
#undef C1_BODY

    // epilogue: store raw + fused stats
    const size_t outbase = (size_t)n * 2048;
    #pragma unroll
    for (int m = 0; m < 2; ++m)
        #pragma unroll
        for (int nt = 0; nt < 4; ++nt)
            #pragma unroll
            for (int j = 0; j < 4; ++j) {
                int b = m * 16 + (lane >> 4) * 4 + j;
                int o = nt * 16 + (lane & 15);
                out1[outbase + b * 64 + o] = f2bfx(acc[m][nt][j]);
            }
    #pragma unroll
    for (int nt = 0; nt < 4; ++nt) {
        float s = 0.f, q = 0.f;
        #pragma unroll
        for (int m = 0; m < 2; ++m)
            #pragma unroll
            for (int j = 0; j < 4; ++j) { float v = acc[m][nt][j]; s += v; q += v * v; }
        s += __shfl_xor(s, 16); s += __shfl_xor(s, 32);
        q += __shfl_xor(q, 16); q += __shfl_xor(q, 32);
        if (lane < 16) {
            atomicAdd(&Ls[nt * 16 + lane], s);
            atomicAdd(&Ls[64 + nt * 16 + lane], q);
        }
    }
    __syncthreads();
    if (tid < 128) atomicAdd(&st[(blockIdx.x & (ST_STRIPES - 1)) * 128 + tid], Ls[tid]);
}

// ---- conv2: wave-private pipeline + register-resident BN1 coefficients ----
__global__ __launch_bounds__(256) void conv2_kernel(
    const ushort* __restrict__ out1raw, const int* __restrict__ idx2,
    const ushort* __restrict__ w2p, const float* __restrict__ ac1,
    ushort* __restrict__ out2, float* __restrict__ st)
{
    __shared__ __align__(16) ushort As[4 * 2 * 32 * 72];   // per-wave double-buffered A
    __shared__ float Ls[128];
    const int tid = threadIdx.x;
    const int lane = tid & 63, wv = tid >> 6;
    const int n = __builtin_amdgcn_readfirstlane(blockIdx.x * 4 + wv);
    const int chg = lane & 7, bq = lane >> 3;   // lane owns 8-ch group chg, 4 b-rows bq*4..+3
    const int fr = (lane & 15) * 72, fc = (lane >> 4) * 8;
    ushort* Ab0 = As + wv * (2 * 32 * 72);
    ushort* Ab1 = Ab0 + 32 * 72;
    const int* idxn = idx2 + n * 9;
    const ushort* wbase = w2p + (lane & 15) * 64 + fc;

    // BN1 coefficients for this lane's 8 channels -> registers
    float a8[8], c8[8];
    {
        const float4 av0 = *(const float4*)(ac1 + chg * 8);
        const float4 av1 = *(const float4*)(ac1 + chg * 8 + 4);
        const float4 cv0 = *(const float4*)(ac1 + 64 + chg * 8);
        const float4 cv1 = *(const float4*)(ac1 + 64 + chg * 8 + 4);
        a8[0]=av0.x; a8[1]=av0.y; a8[2]=av0.z; a8[3]=av0.w;
        a8[4]=av1.x; a8[5]=av1.y; a8[6]=av1.z; a8[7]=av1.w;
        c8[0]=cv0.x; c8[1]=cv0.y; c8[2]=cv0.z; c8[3]=cv0.w;
        c8[4]=cv1.x; c8[5]=cv1.y; c8[6]=cv1.z; c8[7]=cv1.w;
    }
    if (tid < 128) Ls[tid] = 0.f;
    __syncthreads();

    f32x4_t acc[2][4];
    #pragma unroll
    for (int m = 0; m < 2; ++m)
        #pragma unroll
        for (int nt = 0; nt < 4; ++nt) acc[m][nt] = (f32x4_t){0.f, 0.f, 0.f, 0.f};

    int4 A0[4], A1[4];

#define C2_LOAD(K, A) { \
    const ushort* rp = out1raw + (size_t)idxn[K] * 2048 + bq * 256 + chg * 8; \
    A[0] = *(const int4*)rp;         A[1] = *(const int4*)(rp + 64); \
    A[2] = *(const int4*)(rp + 128); A[3] = *(const int4*)(rp + 192); }

#define C2_BODY(K, A, ab) { \
    const ushort* wp = wbase + (K) * 4096; \
    short8_t b0 = *(const short8_t*)(wp);        short8_t b1 = *(const short8_t*)(wp + 32); \
    short8_t b2 = *(const short8_t*)(wp + 1024); short8_t b3 = *(const short8_t*)(wp + 1056); \
    short8_t b4 = *(const short8_t*)(wp + 2048); short8_t b5 = *(const short8_t*)(wp + 2080); \
    short8_t b6 = *(const short8_t*)(wp + 3072); short8_t b7 = *(const short8_t*)(wp + 3104); \
    int4 t0 = bn8(A[0], a8, c8), t1 = bn8(A[1], a8, c8); \
    int4 t2 = bn8(A[2], a8, c8), t3 = bn8(A[3], a8, c8); \
    ushort* wr = (ab) + bq * 288 + chg * 8; \
    *(int4*)(wr) = t0; *(int4*)(wr + 72) = t1; \
    *(int4*)(wr + 144) = t2; *(int4*)(wr + 216) = t3; \
    asm volatile("" ::: "memory"); \
    short8_t af00 = *(const short8_t*)((ab) + fr + fc); \
    short8_t af01 = *(const short8_t*)((ab) + fr + 32 + fc); \
    short8_t af10 = *(const short8_t*)((ab) + fr + 1152 + fc); \
    short8_t af11 = *(const short8_t*)((ab) + fr + 1184 + fc); \
    asm volatile("" ::: "memory"); \
    acc[0][0] = MF(af00, b0, acc[0][0]); acc[0][0] = MF(af01, b1, acc[0][0]); \
    acc[0][1] = MF(af00, b2, acc[0][1]); acc[0][1] = MF(af01, b3, acc[0][1]); \
    acc[0][2] = MF(af00, b4, acc[0][2]); acc[0][2] = MF(af01, b5, acc[0][2]); \
    acc[0][3] = MF(af00, b6, acc[0][3]); acc[0][3] = MF(af01, b7, acc[0][3]); \
    acc[1][0] = MF(af10, b0, acc[1][0]); acc[1][0] = MF(af11, b1, acc[1][0]); \
    acc[1][1] = MF(af10, b2, acc[1][1]); acc[1][1] = MF(af11, b3, acc[1][1]); \
    acc[1][2] = MF(af10, b4, acc[1][2]); acc[1][2] = MF(af11, b5, acc[1][2]); \
    acc[1][3] = MF(af10, b6, acc[1][3]); acc[1][3] = MF(af11, b7, acc[1][3]); }

    C2_LOAD(0, A0);
    for (int t = 0; t < 4; ++t) {
        C2_LOAD(2 * t + 1, A1);
        C2_BODY(2 * t, A0, Ab0);
        C2_LOAD(2 * t + 2, A0);
        C2_BODY(2 * t + 1, A1, Ab1);
    }
    C2_BODY(8, A0, Ab0);
#undef C2_LOAD
#undef C2_BODY

    // epilogue: store + fused stats
    const size_t outbase = (size_t)n * 2048;
    #pragma unroll
    for (int m = 0; m < 2; ++m)
        #pragma unroll
        for (int nt = 0; nt < 4; ++nt)
            #pragma unroll
            for (int j = 0; j < 4; ++j) {
                int b = m * 16 + (lane >> 4) * 4 + j;
                int o = nt * 16 + (lane & 15);
                out2[outbase + b * 64 + o] = f2bfx(acc[m][nt][j]);
            }
    #pragma unroll
    for (int nt = 0; nt < 4; ++nt) {
        float s = 0.f, q = 0.f;
        #pragma unroll
        for (int m = 0; m < 2; ++m)
            #pragma unroll
            for (int j = 0; j < 4; ++j) { float v = acc[m][nt][j]; s += v; q += v * v; }
        s += __shfl_xor(s, 16); s += __shfl_xor(s, 32);
        q += __shfl_xor(q, 16); q += __shfl_xor(q, 32);
        if (lane < 16) {
            atomicAdd(&Ls[nt * 16 + lane], s);
            atomicAdd(&Ls[64 + nt * 16 + lane], q);
        }
    }
    __syncthreads();
    if (tid < 128) atomicAdd(&st[(blockIdx.x & (ST_STRIPES - 1)) * 128 + tid], Ls[tid]);
}

// ---- identity: pooled-gather x We (B-frags direct from global), fused stats ----
__global__ __launch_bounds__(256) void ident_kernel(
    const ushort* __restrict__ xt, const int* __restrict__ pool_idx,
    const ushort* __restrict__ wep, ushort* __restrict__ identt,
    float* __restrict__ st)
{
    __shared__ __align__(16) ushort As[256 * 40];
    __shared__ float Ls[128];
    const int tid = threadIdx.x;
    const int lane = tid & 63, wv = tid >> 6;
    const int nbase = blockIdx.x * 8;
    const int n_l = tid >> 5, b = tid & 31;

    if (tid < 128) Ls[tid] = 0.f;
    __syncthreads();

    float pa[32];
    #pragma unroll
    for (int i = 0; i < 32; ++i) pa[i] = 0.f;
    for (int kp = 0; kp < 4; ++kp) {
        int rrow = pool_idx[(nbase + n_l) * 4 + kp];
        const int4* src = (const int4*)(xt + (size_t)rrow * 1024 + b * 32);
        #pragma unroll
        for (int j = 0; j < 4; ++j) {
            int4 v = src[j];
            const ushort* pv = (const ushort*)&v;
            #pragma unroll
            for (int e = 0; e < 8; ++e) pa[j * 8 + e] += bf2f(pv[e]);
        }
    }
    {
        int4* dst = (int4*)(As + (n_l * 32 + b) * 40);
        #pragma unroll
        for (int j = 0; j < 4; ++j) {
            int4 v; ushort* pv = (ushort*)&v;
            #pragma unroll
            for (int e = 0; e < 8; ++e) pv[e] = f2bfx(pa[j * 8 + e] * 0.25f);
            dst[j] = v;
        }
    }
    asm volatile("" ::: "memory");

    short8_t af[4], bfr[4];
    #pragma unroll
    for (int m = 0; m < 4; ++m)
        af[m] = *(const short8_t*)(As + (wv * 64 + m * 16 + (lane & 15)) * 40 + (lane >> 4) * 8);
    const ushort* wpf = wep + (lane & 15) * 32 + (lane >> 4) * 8;
    #pragma unroll
    for (int nt = 0; nt < 4; ++nt)
        bfr[nt] = *(const short8_t*)(wpf + nt * 512);

    f32x4_t acc[4][4];
    #pragma unroll
    for (int m = 0; m < 4; ++m)
        #pragma unroll
        for (int nt = 0; nt < 4; ++nt) acc[m][nt] = (f32x4_t){0.f, 0.f, 0.f, 0.f};
    #pragma unroll
    for (int m = 0; m < 4; ++m)
        #pragma unroll
        for (int nt = 0; nt < 4; ++nt)
            acc[m][nt] = MF(af[m], bfr[nt], acc[m][nt]);

    #pragma unroll
    for (int m = 0; m < 4; ++m)
        #pragma unroll
        for (int nt = 0; nt < 4; ++nt)
            #pragma unroll
            for (int j = 0; j < 4; ++j) {
                int row = wv * 64 + m * 16 + (lane >> 4) * 4 + j;
                int nl = row >> 5, bb = row & 31, col = nt * 16 + (lane & 15);
                identt[(size_t)(nbase + nl) * 2048 + bb * 64 + col] = f2bfx(acc[m][nt][j]);
            }
    #pragma unroll
    for (int nt = 0; nt < 4; ++nt) {
        float s = 0.f, q = 0.f;
        #pragma unroll
        for (int m = 0; m < 4; ++m)
            #pragma unroll
            for (int j = 0; j < 4; ++j) { float v = acc[m][nt][j]; s += v; q += v * v; }
        s += __shfl_xor(s, 16); s += __shfl_xor(s, 32);
        q += __shfl_xor(q, 16); q += __shfl_xor(q, 32);
        if (lane < 16) {
            atomicAdd(&Ls[nt * 16 + lane], s);
            atomicAdd(&Ls[64 + nt * 16 + lane], q);
        }
    }
    __syncthreads();
    if (tid < 128) atomicAdd(&st[(blockIdx.x & (ST_STRIPES - 1)) * 128 + tid], Ls[tid]);
}

// ---- finalize BN affine from striped partials ----
__global__ void finalize_kernel(const float* __restrict__ st, const float* __restrict__ g,
                                const float* __restrict__ bet, float* __restrict__ ac)
{
    int o = threadIdx.x;
    if (o >= 64) return;
    float s = 0.f, q = 0.f;
    for (int i = 0; i < ST_STRIPES; ++i) { s += st[i * 128 + o]; q += st[i * 128 + 64 + o]; }
    float mean = s * (1.0f / MTOT);
    float var  = q * (1.0f / MTOT) - mean * mean;
    float a = g[o] * rsqrtf(var + 1e-5f);
    ac[o] = a;
    ac[64 + o] = bet[o] - a * mean;
}

__global__ void finalize23_kernel(
    const float* __restrict__ st2, const float* __restrict__ g2, const float* __restrict__ b2,
    const float* __restrict__ st3, const float* __restrict__ g3, const float* __restrict__ b3,
    float* __restrict__ ac2, float* __restrict__ ac3)
{
    int o = threadIdx.x;
    if (o >= 64) return;
    const float* st = blockIdx.x ? st3 : st2;
    const float* g  = blockIdx.x ? g3  : g2;
    const float* bt = blockIdx.x ? b3  : b2;
    float* ac       = blockIdx.x ? ac3 : ac2;
    float s = 0.f, q = 0.f;
    for (int i = 0; i < ST_STRIPES; ++i) { s += st[i * 128 + o]; q += st[i * 128 + 64 + o]; }
    float mean = s * (1.0f / MTOT);
    float var  = q * (1.0f / MTOT) - mean * mean;
    float a = g[o] * rsqrtf(var + 1e-5f);
    ac[o] = a;
    ac[64 + o] = bt[o] - a * mean;
}

// ---- final: d_out[bo][n] = relu(a2*out2 + c2 + a3*identt + c3), with transpose ----
__global__ __launch_bounds__(256) void final_combine_kernel(
    const ushort* __restrict__ out2, const ushort* __restrict__ idt,
    const float* __restrict__ ac2, const float* __restrict__ ac3,
    float* __restrict__ dout)
{
    __shared__ float tile[64][65];
    const int tid = threadIdx.x;
    const int n0 = blockIdx.x * 64, bo0 = blockIdx.y * 64;
    const int lane64 = tid & 63, rb = (tid >> 6) * 16;
    const int o = lane64;  // bo0 is a multiple of 64
    const float a2 = ac2[o], c2 = ac2[64 + o], a3 = ac3[o], c3 = ac3[64 + o];
    #pragma unroll
    for (int r = 0; r < 16; ++r) {
        int n_l = rb + r;
        size_t p = (size_t)(n0 + n_l) * 2048 + bo0 + lane64;
        float v = a2 * bf2f(out2[p]) + c2 + a3 * bf2f(idt[p]) + c3;
        tile[n_l][lane64] = fmaxf(v, 0.f);
    }
    __syncthreads();
    #pragma unroll
    for (int r = 0; r < 16; ++r) {
        int bo_l = rb + r;
        dout[(size_t)(bo0 + bo_l) * NOUT + n0 + lane64] = tile[lane64][bo_l];
    }
}

extern "C" void kernel_launch(void* const* d_in, const int* in_sizes, int n_in,
                              void* d_out, int out_size, void* d_ws, size_t ws_size,
                              hipStream_t stream)
{
    const float* x     = (const float*)d_in[0];
    const float* W1    = (const float*)d_in[1];
    const float* W2    = (const float*)d_in[3];
    const float* We    = (const float*)d_in[5];
    const float* g1    = (const float*)d_in[7];
    const float* beta1 = (const float*)d_in[8];
    const float* g2    = (const float*)d_in[9];
    const float* beta2 = (const float*)d_in[10];
    const float* g3    = (const float*)d_in[11];
    const float* beta3 = (const float*)d_in[12];
    const int* idx1    = (const int*)d_in[13];
    const int* idx2    = (const int*)d_in[14];
    const int* pool_idx= (const int*)d_in[15];
    float* dout = (float*)d_out;

    char* ws = (char*)d_ws;
    const size_t off_xt   = 0;                    // 67108864
    const size_t off_out1 = 67108864;             // 33554432
    const size_t off_out2 = 100663296;            // 33554432
    const size_t off_id   = 134217728;             // 33554432
    const size_t off_w1p  = 167772160;             // 36864
    const size_t off_w2p  = 167809024;             // 73728
    const size_t off_wep  = 167882752;             // 4096
    const size_t off_st   = 167886848;             // 3 * 64*128*4 = 98304
    const size_t off_ac   = 167985152;             // 1536
    const size_t need     = 167986688;
    if (ws_size < need) return;  // insufficient workspace — fail visibly

    ushort* xt   = (ushort*)(ws + off_xt);
    ushort* out1 = (ushort*)(ws + off_out1);
    ushort* out2 = (ushort*)(ws + off_out2);
    ushort* idt  = (ushort*)(ws + off_id);
    ushort* w1p  = (ushort*)(ws + off_w1p);
    ushort* w2p  = (ushort*)(ws + off_w2p);
    ushort* wep  = (ushort*)(ws + off_wep);
    float*  st1  = (float*)(ws + off_st);
    float*  st2  = st1 + 64 * 128;
    float*  st3  = st1 + 2 * 64 * 128;
    float*  ac1  = (float*)(ws + off_ac);
    float*  ac2  = ac1 + 128;
    float*  ac3  = ac1 + 256;

    prep_w_kernel<<<224, 256, 0, stream>>>(W1, W2, We, w1p, w2p, wep, st1);
    transpose_x_kernel<<<dim3(512, 16), 256, 0, stream>>>(x, xt);
    conv1_kernel<<<2048, 256, 0, stream>>>(xt, idx1, w1p, out1, st1);
    ident_kernel<<<1024, 256, 0, stream>>>(xt, pool_idx, wep, idt, st3);
    finalize_kernel<<<1, 64, 0, stream>>>(st1, g1, beta1, ac1);
    conv2_kernel<<<2048, 256, 0, stream>>>(out1, idx2, w2p, ac1, out2, st2);
    finalize23_kernel<<<2, 64, 0, stream>>>(st2, g2, beta2, st3, g3, beta3, ac2, ac3);
    final_combine_kernel<<<dim3(128, 32), 256, 0, stream>>>(out2, idt, ac2, ac3, dout);
}